// Round 3
// baseline (718.255 us; speedup 1.0000x reference)
//
#include <hip/hip_runtime.h>

// SetEncoderPointNet — split streaming version (bf16x3 split-precision MFMA).
//
// out = x @ w2[:, :64]^T + v,  v[bn] = (max_m(x@w1^T) + b1) @ w2[:, 64:]^T.
// Kernel A (compute_vv): read-stream x once, produce vv (2048x256 f32) in ws.
// Kernel B (apply_out):  read-stream x again, GEMM + vv broadcast, write-stream out.
// Split precision: a*b ~= ahi*bhi + ahi*blo + alo*bhi (3 bf16 MFMA passes).

#define CIN  64
#define KPAD 72            // padded k-stride in LDS shorts (2-way bank alias only)
#define PLANE 18432        // 256 * 72 shorts per LDS plane

typedef __attribute__((ext_vector_type(8))) short short8;
typedef __attribute__((ext_vector_type(4))) float float4v;

__device__ __forceinline__ short f2bf(float f) {
    union { float f; unsigned u; } c; c.f = f;
    unsigned u = c.u;
    unsigned r = (u + 0x7FFFu + ((u >> 16) & 1u)) >> 16;  // RNE
    return (short)r;
}
__device__ __forceinline__ float bf2f(short s) {
    union { unsigned u; float f; } c;
    c.u = ((unsigned)(unsigned short)s) << 16;
    return c.f;
}

// ws layout (shorts): [0: w1 hi 16K | 16K: w1 lo | 32K: w2x hi | 48K: w2x lo |
//   64K..: w2zt fp32 (65536 floats) | short-off 196608: vv fp32 (2048*256 floats)]
__global__ void prep_weights(const float* __restrict__ w1,
                             const float* __restrict__ w2,
                             short* __restrict__ wsS) {
    int i = blockIdx.x * 256 + threadIdx.x;
    if (i < 16384) {                       // w1 [d][k] row-major
        float f = w1[i];
        short h = f2bf(f);
        wsS[i] = h;
        wsS[16384 + i] = f2bf(f - bf2f(h));
    } else if (i < 32768) {                // w2x: first 64 cols of w2 rows
        int q = i - 16384;
        int j = q >> 6, k = q & 63;
        float f = w2[j * 320 + k];
        short h = f2bf(f);
        wsS[32768 + q] = h;
        wsS[49152 + q] = f2bf(f - bf2f(h));
    } else if (i < 98304) {                // w2zt[d][j] = w2[j][64+d], fp32
        int q = i - 32768;
        int d = q >> 8, j = q & 255;
        ((float*)(wsS + 65536))[q] = w2[j * 320 + 64 + d];
    }
}

// ---------------- Kernel A: vv[bn][j] = (max_m(x@w1^T)+b1) @ w2zt ----------------
__global__ __launch_bounds__(256, 2)
void compute_vv(const float* __restrict__ x,
                const float* __restrict__ b1,
                const short* __restrict__ w1p,
                const float* __restrict__ w2zt,
                float* __restrict__ vvg) {
    __shared__ short wlds[2 * PLANE];
    __shared__ float red[1024];
    __shared__ float zv[256];

    const int tid = threadIdx.x;
    const int bn  = blockIdx.x;
    const int w   = tid >> 6;
    const int l   = tid & 63;
    const int dl  = l & 15;
    const int q   = l >> 4;
    const int mw  = w * 64;
    const float* __restrict__ xg = x + (size_t)bn * (256 * CIN);

    float4 xa0[4][2], xa1[4][2];
#pragma unroll
    for (int t = 0; t < 4; ++t)
#pragma unroll
        for (int s = 0; s < 2; ++s) {
            const float* p = xg + (mw + t * 16 + dl) * CIN + s * 32 + q * 8;
            xa0[t][s] = *(const float4*)p;
            xa1[t][s] = *(const float4*)(p + 4);
        }

    {   // stage w1 hi/lo planes
        const short8* src = (const short8*)w1p;
#pragma unroll
        for (int it = 0; it < 16; ++it) {
            int i = tid + 256 * it;
            int plane = i >> 11;
            int c = i & 2047;
            int row = c >> 3, k = (c & 7) << 3;
            *(short8*)&wlds[plane * PLANE + row * KPAD + k] = src[i];
        }
    }

    short8 ahi[4][2], alo[4][2];
#pragma unroll
    for (int t = 0; t < 4; ++t)
#pragma unroll
        for (int s = 0; s < 2; ++s) {
            float e[8];
            e[0] = xa0[t][s].x; e[1] = xa0[t][s].y; e[2] = xa0[t][s].z; e[3] = xa0[t][s].w;
            e[4] = xa1[t][s].x; e[5] = xa1[t][s].y; e[6] = xa1[t][s].z; e[7] = xa1[t][s].w;
#pragma unroll
            for (int j = 0; j < 8; ++j) {
                short h = f2bf(e[j]);
                ahi[t][s][j] = h;
                alo[t][s][j] = f2bf(e[j] - bf2f(h));
            }
        }
    __syncthreads();

#pragma unroll
    for (int chunk = 0; chunk < 4; ++chunk) {
        const int d0c = chunk * 64;
        short8 bhi[4][2], blo[4][2];
#pragma unroll
        for (int dt = 0; dt < 4; ++dt)
#pragma unroll
            for (int s = 0; s < 2; ++s) {
                int off = (d0c + dt * 16 + dl) * KPAD + s * 32 + q * 8;
                bhi[dt][s] = *(const short8*)&wlds[off];
                blo[dt][s] = *(const short8*)&wlds[off + PLANE];
            }
        float4v acc[4][4];
#pragma unroll
        for (int t = 0; t < 4; ++t)
#pragma unroll
            for (int dt = 0; dt < 4; ++dt) {
                float4v a = {0.f, 0.f, 0.f, 0.f};
#pragma unroll
                for (int s = 0; s < 2; ++s) {
                    a = __builtin_amdgcn_mfma_f32_16x16x32_bf16(ahi[t][s], bhi[dt][s], a, 0, 0, 0);
                    a = __builtin_amdgcn_mfma_f32_16x16x32_bf16(ahi[t][s], blo[dt][s], a, 0, 0, 0);
                    a = __builtin_amdgcn_mfma_f32_16x16x32_bf16(alo[t][s], bhi[dt][s], a, 0, 0, 0);
                }
                acc[t][dt] = a;
            }
#pragma unroll
        for (int dt = 0; dt < 4; ++dt) {
            float mx = -3.0e38f;
#pragma unroll
            for (int t = 0; t < 4; ++t)
#pragma unroll
                for (int r = 0; r < 4; ++r) mx = fmaxf(mx, acc[t][dt][r]);
            mx = fmaxf(mx, __shfl_xor(mx, 16));
            mx = fmaxf(mx, __shfl_xor(mx, 32));
            if (q == 0) red[w * 256 + d0c + dt * 16 + dl] = mx;
        }
    }
    __syncthreads();
    zv[tid] = fmaxf(fmaxf(red[tid], red[256 + tid]),
                    fmaxf(red[512 + tid], red[768 + tid])) + b1[tid];
    __syncthreads();

    {   // v[j] = zv . w2zt[:,j], K split over 4 thread groups
        const int jq = tid & 63;
        const int dpart = tid >> 6;
        const float4* wz4 = (const float4*)w2zt;
        float4 vacc = make_float4(0.f, 0.f, 0.f, 0.f);
#pragma unroll 4
        for (int d = 0; d < 64; ++d) {
            int dd = dpart * 64 + d;
            float s = zv[dd];
            float4 wv = wz4[dd * 64 + jq];
            vacc.x = fmaf(s, wv.x, vacc.x);
            vacc.y = fmaf(s, wv.y, vacc.y);
            vacc.z = fmaf(s, wv.z, vacc.z);
            vacc.w = fmaf(s, wv.w, vacc.w);
        }
        ((float4*)red)[dpart * 64 + jq] = vacc;
    }
    __syncthreads();
    vvg[bn * 256 + tid] = red[tid] + red[256 + tid] + red[512 + tid] + red[768 + tid];
}

// ---------------- Kernel B: out = x @ w2x^T + vv[bn] (streaming) ----------------
__global__ __launch_bounds__(256, 2)
void apply_out(const float* __restrict__ x,
               const short* __restrict__ w2xp,
               const float* __restrict__ vvg,
               float* __restrict__ out) {
    __shared__ short wlds[2 * PLANE];
    __shared__ float vvs[256];

    const int tid = threadIdx.x;
    const int bn  = blockIdx.x;
    const int w   = tid >> 6;
    const int l   = tid & 63;
    const int dl  = l & 15;
    const int q   = l >> 4;
    const int mw  = w * 64;
    const float* __restrict__ xg = x + (size_t)bn * (256 * CIN);

    float4 xa0[4][2], xa1[4][2];
#pragma unroll
    for (int t = 0; t < 4; ++t)
#pragma unroll
        for (int s = 0; s < 2; ++s) {
            const float* p = xg + (mw + t * 16 + dl) * CIN + s * 32 + q * 8;
            xa0[t][s] = *(const float4*)p;
            xa1[t][s] = *(const float4*)(p + 4);
        }

    {   // stage w2x hi/lo planes
        const short8* src = (const short8*)w2xp;
#pragma unroll
        for (int it = 0; it < 16; ++it) {
            int i = tid + 256 * it;
            int plane = i >> 11;
            int c = i & 2047;
            int row = c >> 3, k = (c & 7) << 3;
            *(short8*)&wlds[plane * PLANE + row * KPAD + k] = src[i];
        }
    }
    vvs[tid] = vvg[bn * 256 + tid];

    short8 ahi[4][2], alo[4][2];
#pragma unroll
    for (int t = 0; t < 4; ++t)
#pragma unroll
        for (int s = 0; s < 2; ++s) {
            float e[8];
            e[0] = xa0[t][s].x; e[1] = xa0[t][s].y; e[2] = xa0[t][s].z; e[3] = xa0[t][s].w;
            e[4] = xa1[t][s].x; e[5] = xa1[t][s].y; e[6] = xa1[t][s].z; e[7] = xa1[t][s].w;
#pragma unroll
            for (int j = 0; j < 8; ++j) {
                short h = f2bf(e[j]);
                ahi[t][s][j] = h;
                alo[t][s][j] = f2bf(e[j] - bf2f(h));
            }
        }
    __syncthreads();

    float* __restrict__ og = out + (size_t)bn * (256 * 256);
#pragma unroll
    for (int chunk = 0; chunk < 4; ++chunk) {
        const int d0c = chunk * 64;
        short8 bhi[4][2], blo[4][2];
#pragma unroll
        for (int dt = 0; dt < 4; ++dt)
#pragma unroll
            for (int s = 0; s < 2; ++s) {
                int off = (d0c + dt * 16 + dl) * KPAD + s * 32 + q * 8;
                bhi[dt][s] = *(const short8*)&wlds[off];
                blo[dt][s] = *(const short8*)&wlds[off + PLANE];
            }
        float vdt[4];
#pragma unroll
        for (int dt = 0; dt < 4; ++dt) vdt[dt] = vvs[d0c + dt * 16 + dl];
#pragma unroll
        for (int t = 0; t < 4; ++t)
#pragma unroll
            for (int dt = 0; dt < 4; ++dt) {
                float4v a = {0.f, 0.f, 0.f, 0.f};
#pragma unroll
                for (int s = 0; s < 2; ++s) {
                    a = __builtin_amdgcn_mfma_f32_16x16x32_bf16(ahi[t][s], bhi[dt][s], a, 0, 0, 0);
                    a = __builtin_amdgcn_mfma_f32_16x16x32_bf16(ahi[t][s], blo[dt][s], a, 0, 0, 0);
                    a = __builtin_amdgcn_mfma_f32_16x16x32_bf16(alo[t][s], bhi[dt][s], a, 0, 0, 0);
                }
                const int rowb = (mw + t * 16 + q * 4) * 256 + d0c + dt * 16 + dl;
#pragma unroll
                for (int r = 0; r < 4; ++r)
                    __builtin_nontemporal_store(a[r] + vdt[dt], &og[rowb + r * 256]);
            }
    }
}

extern "C" void kernel_launch(void* const* d_in, const int* in_sizes, int n_in,
                              void* d_out, int out_size, void* d_ws, size_t ws_size,
                              hipStream_t stream) {
    const float* x  = (const float*)d_in[0];
    const float* w1 = (const float*)d_in[1];
    const float* b1 = (const float*)d_in[2];
    const float* w2 = (const float*)d_in[3];
    short* wsS = (short*)d_ws;
    float* out = (float*)d_out;
    float* vvg = (float*)(wsS + 196608);          // byte offset 384 KB, 2 MB buffer

    hipLaunchKernelGGL(prep_weights, dim3(384), dim3(256), 0, stream, w1, w2, wsS);
    hipLaunchKernelGGL(compute_vv, dim3(2048), dim3(256), 0, stream,
                       x, b1, wsS, (const float*)(wsS + 65536), vvg);
    hipLaunchKernelGGL(apply_out, dim3(2048), dim3(256), 0, stream,
                       x, wsS + 32768, vvg, out);
}